// Round 17
// baseline (119.620 us; speedup 1.0000x reference)
//
#include <hip/hip_runtime.h>
#include <math.h>

namespace {

using bf16x8 = __attribute__((ext_vector_type(8))) short;
using f32x4  = __attribute__((ext_vector_type(4))) float;

constexpr int D   = 40;     // n_embed
constexpr int HS  = 10;     // head size
constexpr int NH  = 4;      // heads
constexpr int TT  = 2048;   // seq len
constexpr int BB  = 16;     // batch
constexpr int ROWS = BB * TT;       // 32768
constexpr int PE  = 16;             // q/k bf16 row width (cols 10-15 zero)
constexpr int VR  = 11;             // vT rows: 10 V + 1 ones (for l via MFMA)
constexpr float LOG2E = 1.4426950408889634f;

__device__ inline unsigned short f2b(float x) {   // fp32 -> bf16 RNE
    unsigned int u = __float_as_uint(x);
    unsigned int r = (u + 0x7fffu + ((u >> 16) & 1u)) >> 16;
    return (unsigned short)r;
}

__device__ inline float dot40(const float* __restrict__ xr,
                              const float* __restrict__ w) {
    float s0 = 0.f, s1 = 0.f, s2 = 0.f, s3 = 0.f;
    const float4* w4 = reinterpret_cast<const float4*>(w);
    #pragma unroll
    for (int i = 0; i < 10; ++i) {
        float4 t = w4[i];
        s0 = fmaf(xr[4*i+0], t.x, s0);
        s1 = fmaf(xr[4*i+1], t.y, s1);
        s2 = fmaf(xr[4*i+2], t.z, s2);
        s3 = fmaf(xr[4*i+3], t.w, s3);
    }
    return (s0 + s1) + (s2 + s3);
}

// ------- Kernel 1: LN1 + QKV, 8 threads per row (head x e-half) -------------
// R16-passing version, unchanged.
__global__ __launch_bounds__(256) void k_ln_qkv(
    const float* __restrict__ x,  const float* __restrict__ Wq,
    const float* __restrict__ Wk, const float* __restrict__ Wv,
    const float* __restrict__ g1, const float* __restrict__ be1,
    float* __restrict__ xn, unsigned short* __restrict__ qb,
    unsigned short* __restrict__ kb, unsigned short* __restrict__ vT)
{
    __shared__ float wt_s[3*NH*HS*D];   // transposed: [which][h][e][d]
    __shared__ float g_s[D], b_s[D];
    const int tid = threadIdx.x;
    {
        const float4* Wq4 = reinterpret_cast<const float4*>(Wq);
        const float4* Wk4 = reinterpret_cast<const float4*>(Wk);
        const float4* Wv4 = reinterpret_cast<const float4*>(Wv);
        for (int i4 = tid; i4 < NH*D*HS/4; i4 += 256) {
            float4 qv = Wq4[i4], kv = Wk4[i4], vv = Wv4[i4];
            const float* qf = reinterpret_cast<const float*>(&qv);
            const float* kf = reinterpret_cast<const float*>(&kv);
            const float* vf = reinterpret_cast<const float*>(&vv);
            #pragma unroll
            for (int c = 0; c < 4; ++c) {
                const int i = i4*4 + c;
                const int h = i / (D*HS), r = i % (D*HS);
                const int d = r / HS, e = r % HS;
                const int to = (h*HS + e)*D + d;
                wt_s[to]              = qf[c];
                wt_s[NH*HS*D + to]    = kf[c];
                wt_s[2*NH*HS*D + to]  = vf[c];
            }
        }
    }
    if (tid < D) { g_s[tid] = g1[tid]; b_s[tid] = be1[tid]; }
    __syncthreads();

    const int gid = blockIdx.x * 256 + tid;
    const int eh  = gid & 1;            // e-half: 0 -> e 0..4, 1 -> e 5..9
    const int h   = (gid >> 1) & 3;
    const int row = gid >> 3;

    float xr[D];
    const float4* xp = reinterpret_cast<const float4*>(x + (size_t)row * D);
    #pragma unroll
    for (int i = 0; i < D/4; ++i) {
        float4 t4 = xp[i];
        xr[4*i+0]=t4.x; xr[4*i+1]=t4.y; xr[4*i+2]=t4.z; xr[4*i+3]=t4.w;
    }
    float mu = 0.f;
    #pragma unroll
    for (int d = 0; d < D; ++d) mu += xr[d];
    mu *= (1.f/D);
    float var = 0.f;
    #pragma unroll
    for (int d = 0; d < D; ++d) { float dd = xr[d]-mu; var += dd*dd; }
    var *= (1.f/D);
    const float rs = rsqrtf(var + 1e-5f);
    #pragma unroll
    for (int d = 0; d < D; ++d) xr[d] = (xr[d]-mu)*rs*g_s[d] + b_s[d];

    if ((gid & 7) == 0) {
        float4* xo = reinterpret_cast<float4*>(xn + (size_t)row * D);
        #pragma unroll
        for (int i = 0; i < D/4; ++i) {
            float4 t4; t4.x=xr[4*i+0]; t4.y=xr[4*i+1]; t4.z=xr[4*i+2]; t4.w=xr[4*i+3];
            xo[i] = t4;
        }
    }

    const int b = row >> 11;
    const int t = row & (TT-1);
    const int bh = b*NH + h;
    const int e0 = eh * 5;

    float aq[5], ak[5], av[5];
    #pragma unroll
    for (int e = 0; e < 5; ++e) {
        aq[e] = dot40(xr, &wt_s[(h*HS + e0 + e)*D]);
        ak[e] = dot40(xr, &wt_s[NH*HS*D + (h*HS + e0 + e)*D]);
        av[e] = dot40(xr, &wt_s[2*NH*HS*D + (h*HS + e0 + e)*D]);
    }

    // exchange: eh0 sends its k-lows (partner needs them), eh1 sends q-highs.
    float send[5], recv[5];
    #pragma unroll
    for (int j = 0; j < 5; ++j) send[j] = eh ? aq[j] : ak[j];
    #pragma unroll
    for (int j = 0; j < 5; ++j) recv[j] = __shfl_xor(send[j], 1);

    // eh0 owns the full q row (scaled by log2 e); eh1 owns the full k row
    const float scale = eh ? 1.f : LOG2E;
    float lo[5], hi[5];
    #pragma unroll
    for (int j = 0; j < 5; ++j) {
        lo[j] = eh ? recv[j] : aq[j];
        hi[j] = eh ? ak[j]   : recv[j];
    }
    union { unsigned short u[PE]; uint4 v4[2]; } U;
    #pragma unroll
    for (int e = 0; e < PE; ++e)
        U.u[e] = (e < 5) ? f2b(lo[e]*scale)
               : (e < 10) ? f2b(hi[e-5]*scale) : (unsigned short)0;
    unsigned short* dst = (eh ? kb : qb) + ((size_t)bh*TT + t)*PE;
    uint4* d4 = reinterpret_cast<uint4*>(dst);
    d4[0] = U.v4[0]; d4[1] = U.v4[1];

    #pragma unroll
    for (int e = 0; e < 5; ++e)
        vT[((size_t)bh*VR + e0 + e)*TT + t] = f2b(av[e]);
    if (eh) vT[((size_t)bh*VR + HS)*TT + t] = 0x3F80;   // ones row -> l via MFMA
}

// ------- Kernel 2: MFMA flash attention ----------
// R6-proven structure. ONE change vs R16: in-loop load predication removed.
// a0/a1 garbage lanes (g>=2) feed A k-slices 16..31 which multiply kf==0
// (kf predication kept, outside the loop) -> contribute exactly 0; garbage
// is adjacent finite bf16 data (max 16-short overrun from qb lands in kb).
// vf for li>10 reads the clamped row; O rows 11..15 are never stored.
// Unconditional loads let the compiler pipeline them across unroll-4 iters.
__global__ __launch_bounds__(256, 4) void k_attn(
    const unsigned short* __restrict__ qb, const unsigned short* __restrict__ kb,
    const unsigned short* __restrict__ vT, float* __restrict__ ao)
{
    __shared__ __align__(16) unsigned short PT[4][16][40];  // 80B row: 16B-aligned, <=2-way banks
    const int w    = threadIdx.x >> 6;
    const int lane = threadIdx.x & 63;
    const int g    = lane >> 4;
    const int li   = lane & 15;
    const int bh   = blockIdx.y;
    const int i0   = blockIdx.x * 64 + w * 16;
    const size_t bT = (size_t)bh * TT;

    const bf16x8 zero8 = {0,0,0,0,0,0,0,0};
    const f32x4  zacc  = {0.f,0.f,0.f,0.f};

    bf16x8 kf = zero8;                       // B-frag: k[i0+li][8g..8g+7]
    if (g < 2) kf = *reinterpret_cast<const bf16x8*>(kb + (bT + i0 + li)*PE + 8*g);

    f32x4 acc = zacc;
    const unsigned short* vrow = vT + ((size_t)bh*VR + (li <= HS ? li : 0))*TT;
    const unsigned short* qrow = qb + (bT + li)*PE + 8*g;

    #pragma unroll 4
    for (int jt = 0; jt < TT; jt += 32) {
        // unconditional A-frag / V-frag loads (see kernel comment for safety)
        bf16x8 a0 = *reinterpret_cast<const bf16x8*>(qrow + (size_t)(jt     )*PE);
        bf16x8 a1 = *reinterpret_cast<const bf16x8*>(qrow + (size_t)(jt + 16)*PE);
        bf16x8 vf = *reinterpret_cast<const bf16x8*>(vrow + jt + 8*g);

        __builtin_amdgcn_s_setprio(1);
        f32x4 s0 = __builtin_amdgcn_mfma_f32_16x16x32_bf16(a0, kf, zacc, 0, 0, 0);
        f32x4 s1 = __builtin_amdgcn_mfma_f32_16x16x32_bf16(a1, kf, zacc, 0, 0, 0);
        __builtin_amdgcn_s_setprio(0);

        const float p0 = __builtin_amdgcn_exp2f(s0[0]), p1 = __builtin_amdgcn_exp2f(s0[1]);
        const float p2 = __builtin_amdgcn_exp2f(s0[2]), p3 = __builtin_amdgcn_exp2f(s0[3]);
        const float p4 = __builtin_amdgcn_exp2f(s1[0]), p5 = __builtin_amdgcn_exp2f(s1[1]);
        const float p6 = __builtin_amdgcn_exp2f(s1[2]), p7 = __builtin_amdgcn_exp2f(s1[3]);

        unsigned int w0, w1, w2, w3;
        asm("v_cvt_pk_bf16_f32 %0, %1, %2" : "=v"(w0) : "v"(p0), "v"(p1));
        asm("v_cvt_pk_bf16_f32 %0, %1, %2" : "=v"(w1) : "v"(p2), "v"(p3));
        asm("v_cvt_pk_bf16_f32 %0, %1, %2" : "=v"(w2) : "v"(p4), "v"(p5));
        asm("v_cvt_pk_bf16_f32 %0, %1, %2" : "=v"(w3) : "v"(p6), "v"(p7));
        *reinterpret_cast<uint2*>(&PT[w][li][4*g])      = make_uint2(w0, w1);
        *reinterpret_cast<uint2*>(&PT[w][li][16 + 4*g]) = make_uint2(w2, w3);

        bf16x8 pf = *reinterpret_cast<const bf16x8*>(&PT[w][li][8*g]);
        __builtin_amdgcn_s_setprio(1);
        acc = __builtin_amdgcn_mfma_f32_16x16x32_bf16(vf, pf, acc, 0, 0, 0);
        __builtin_amdgcn_s_setprio(0);
    }

    // l for column li lives in acc[2] of lane (g=2, li)  [row 10 = ones row]
    const float l = __shfl(acc[2], 32 + li);
    const float linv = 1.f / l;
    float* orow = ao + (bT + i0 + li) * HS;
    #pragma unroll
    for (int r = 0; r < 4; ++r) {
        const int e = 4*g + r;               // O^T row = e, col = i (lane-local)
        if (e < HS) orow[e] = acc[r] * linv;
    }
}

// ------- Kernel 3: epilogue, 4 threads per row ------------------------------
// R16-passing version, unchanged.
__global__ __launch_bounds__(256) void k_epilogue(
    const float* __restrict__ attn, const float* __restrict__ xn,
    const float* __restrict__ Wp, const float* __restrict__ bp,
    const float* __restrict__ W1, const float* __restrict__ b1,
    const float* __restrict__ W2, const float* __restrict__ b2,
    const float* __restrict__ g2, const float* __restrict__ be2,
    float* __restrict__ out)
{
    __shared__ float wp_s[D*D], w1_s[D*D], w2_s[D*D];
    __shared__ float bp_s[D], b1_s[D], b2_s[D], g_s[D], be_s[D];
    const int tid = threadIdx.x;
    {
        float4* wp4 = reinterpret_cast<float4*>(wp_s);
        float4* w14 = reinterpret_cast<float4*>(w1_s);
        float4* w24 = reinterpret_cast<float4*>(w2_s);
        const float4* Wp4 = reinterpret_cast<const float4*>(Wp);
        const float4* W14 = reinterpret_cast<const float4*>(W1);
        const float4* W24 = reinterpret_cast<const float4*>(W2);
        for (int i = tid; i < D*D/4; i += 256) {
            wp4[i] = Wp4[i]; w14[i] = W14[i]; w24[i] = W24[i];
        }
    }
    if (tid < D) {
        bp_s[tid]=bp[tid]; b1_s[tid]=b1[tid]; b2_s[tid]=b2[tid];
        g_s[tid]=g2[tid]; be_s[tid]=be2[tid];
    }
    __syncthreads();

    const int gid  = blockIdx.x * 256 + tid;
    const int row  = gid >> 2;
    const int q4   = gid & 3;
    const int b0   = q4 * 10;
    const int lane = tid & 63;
    const int base = lane & 60;          // first lane of this row's 4-lane group
    const int b    = row >> 11;
    const int t    = row & (TT-1);

    float cat[D];
    #pragma unroll
    for (int h = 0; h < NH; ++h) {
        const float2* ap = reinterpret_cast<const float2*>(
            attn + ((((size_t)b*NH + h)*TT) + t)*HS);
        #pragma unroll
        for (int e = 0; e < HS/2; ++e) {
            float2 t2 = ap[e];
            cat[h*HS + 2*e] = t2.x; cat[h*HS + 2*e + 1] = t2.y;
        }
    }

    float y[10];
    {
        const float2* xp = reinterpret_cast<const float2*>(xn + (size_t)row*D + b0);
        #pragma unroll
        for (int i = 0; i < 5; ++i) {
            float2 t2 = xp[i];
            y[2*i+0] = t2.x; y[2*i+1] = t2.y;
        }
    }
    #pragma unroll
    for (int d = 0; d < 10; ++d) y[d] += bp_s[b0+d];
    for (int c = 0; c < D; ++c) {
        const float cc = cat[c];
        const float* wr = &wp_s[c*D + b0];
        #pragma unroll
        for (int d = 0; d < 10; ++d) y[d] = fmaf(cc, wr[d], y[d]);
    }

    // LN2 via 4-lane reduce
    float sp = 0.f;
    #pragma unroll
    for (int d = 0; d < 10; ++d) sp += y[d];
    sp += __shfl_xor(sp, 1); sp += __shfl_xor(sp, 2);
    const float mu = sp * (1.f/D);
    float vp = 0.f;
    #pragma unroll
    for (int d = 0; d < 10; ++d) { float dd = y[d]-mu; vp += dd*dd; }
    vp += __shfl_xor(vp, 1); vp += __shfl_xor(vp, 2);
    const float rs = rsqrtf(vp * (1.f/D) + 1e-5f);

    float y2[10];
    #pragma unroll
    for (int d = 0; d < 10; ++d) y2[d] = (y[d]-mu)*rs*g_s[b0+d] + be_s[b0+d];

    float z[D];
    #pragma unroll
    for (int seg = 0; seg < 4; ++seg)
        #pragma unroll
        for (int j = 0; j < 10; ++j)
            z[seg*10 + j] = __shfl(y2[j], base + seg);

    float hd[10];
    #pragma unroll
    for (int d = 0; d < 10; ++d) hd[d] = b1_s[b0+d];
    for (int c = 0; c < D; ++c) {
        const float cc = z[c];
        const float* wr = &w1_s[c*D + b0];
        #pragma unroll
        for (int d = 0; d < 10; ++d) hd[d] = fmaf(cc, wr[d], hd[d]);
    }
    #pragma unroll
    for (int d = 0; d < 10; ++d) hd[d] = fmaxf(hd[d], 0.f);

    float hf[D];
    #pragma unroll
    for (int seg = 0; seg < 4; ++seg)
        #pragma unroll
        for (int j = 0; j < 10; ++j)
            hf[seg*10 + j] = __shfl(hd[j], base + seg);

    float ov[10];
    #pragma unroll
    for (int d = 0; d < 10; ++d) ov[d] = y2[d] + b2_s[b0+d];
    for (int c = 0; c < D; ++c) {
        const float cc = hf[c];
        const float* wr = &w2_s[c*D + b0];
        #pragma unroll
        for (int d = 0; d < 10; ++d) ov[d] = fmaf(cc, wr[d], ov[d]);
    }

    float2* op = reinterpret_cast<float2*>(out + (size_t)row*D + b0);
    #pragma unroll
    for (int i = 0; i < 5; ++i) {
        float2 t2; t2.x = ov[2*i]; t2.y = ov[2*i+1];
        op[i] = t2;
    }
}

} // namespace

extern "C" void kernel_launch(void* const* d_in, const int* in_sizes, int n_in,
                              void* d_out, int out_size, void* d_ws, size_t ws_size,
                              hipStream_t stream) {
    const float* x   = (const float*)d_in[0];
    const float* Wq  = (const float*)d_in[1];
    const float* Wk  = (const float*)d_in[2];
    const float* Wv  = (const float*)d_in[3];
    const float* Wp  = (const float*)d_in[4];
    const float* bp  = (const float*)d_in[5];
    const float* W1  = (const float*)d_in[6];
    const float* b1  = (const float*)d_in[7];
    const float* W2  = (const float*)d_in[8];
    const float* b2  = (const float*)d_in[9];
    const float* g1  = (const float*)d_in[10];
    const float* be1 = (const float*)d_in[11];
    const float* g2  = (const float*)d_in[12];
    const float* be2 = (const float*)d_in[13];

    const size_t N = (size_t)ROWS * D;           // 1,310,720
    float* xn = (float*)d_ws;                    // [ROWS][40] f32
    float* ao = xn + N;                          // [64][2048][10] f32
    unsigned short* qb = (unsigned short*)(ao + N);        // [64][2048][16] bf16
    unsigned short* kb = qb + (size_t)BB*NH*TT*PE;         // follows qb: absorbs a1 overrun
    unsigned short* vT = kb + (size_t)BB*NH*TT*PE;         // [64][11][2048] bf16

    k_ln_qkv<<<ROWS*8/256, 256, 0, stream>>>(x, Wq, Wk, Wv, g1, be1, xn, qb, kb, vT);
    k_attn<<<dim3(TT/64, BB*NH), 256, 0, stream>>>(qb, kb, vT, ao);
    k_epilogue<<<ROWS*4/256, 256, 0, stream>>>(ao, xn, Wp, bp, W1, b1, W2, b2, g2, be2,
                                               (float*)d_out);
}

// Round 18
// 109.928 us; speedup vs baseline: 1.0882x; 1.0882x over previous
//
#include <hip/hip_runtime.h>
#include <math.h>

namespace {

using bf16x8 = __attribute__((ext_vector_type(8))) short;
using f32x4  = __attribute__((ext_vector_type(4))) float;

constexpr int D   = 40;     // n_embed
constexpr int HS  = 10;     // head size
constexpr int NH  = 4;      // heads
constexpr int TT  = 2048;   // seq len
constexpr int BB  = 16;     // batch
constexpr int ROWS = BB * TT;       // 32768
constexpr int PE  = 16;             // q/k bf16 row width (cols 10-15 zero)
constexpr int VR  = 11;             // vT rows: 10 V + 1 ones (for l via MFMA)
constexpr float LOG2E = 1.4426950408889634f;

__device__ inline unsigned short f2b(float x) {   // fp32 -> bf16 RNE
    unsigned int u = __float_as_uint(x);
    unsigned int r = (u + 0x7fffu + ((u >> 16) & 1u)) >> 16;
    return (unsigned short)r;
}

__device__ inline float dot40(const float* __restrict__ xr,
                              const float* __restrict__ w) {
    float s0 = 0.f, s1 = 0.f, s2 = 0.f, s3 = 0.f;
    const float4* w4 = reinterpret_cast<const float4*>(w);
    #pragma unroll
    for (int i = 0; i < 10; ++i) {
        float4 t = w4[i];
        s0 = fmaf(xr[4*i+0], t.x, s0);
        s1 = fmaf(xr[4*i+1], t.y, s1);
        s2 = fmaf(xr[4*i+2], t.z, s2);
        s3 = fmaf(xr[4*i+3], t.w, s3);
    }
    return (s0 + s1) + (s2 + s3);
}

// ------- Kernel 1: LN1 + QKV, 8 threads per row (head x e-half) -------------
__global__ __launch_bounds__(256) void k_ln_qkv(
    const float* __restrict__ x,  const float* __restrict__ Wq,
    const float* __restrict__ Wk, const float* __restrict__ Wv,
    const float* __restrict__ g1, const float* __restrict__ be1,
    float* __restrict__ xn, unsigned short* __restrict__ qb,
    unsigned short* __restrict__ kb, unsigned short* __restrict__ vT)
{
    __shared__ float wt_s[3*NH*HS*D];   // transposed: [which][h][e][d]
    __shared__ float g_s[D], b_s[D];
    const int tid = threadIdx.x;
    {
        const float4* Wq4 = reinterpret_cast<const float4*>(Wq);
        const float4* Wk4 = reinterpret_cast<const float4*>(Wk);
        const float4* Wv4 = reinterpret_cast<const float4*>(Wv);
        for (int i4 = tid; i4 < NH*D*HS/4; i4 += 256) {
            float4 qv = Wq4[i4], kv = Wk4[i4], vv = Wv4[i4];
            const float* qf = reinterpret_cast<const float*>(&qv);
            const float* kf = reinterpret_cast<const float*>(&kv);
            const float* vf = reinterpret_cast<const float*>(&vv);
            #pragma unroll
            for (int c = 0; c < 4; ++c) {
                const int i = i4*4 + c;
                const int h = i / (D*HS), r = i % (D*HS);
                const int d = r / HS, e = r % HS;
                const int to = (h*HS + e)*D + d;
                wt_s[to]              = qf[c];
                wt_s[NH*HS*D + to]    = kf[c];
                wt_s[2*NH*HS*D + to]  = vf[c];
            }
        }
    }
    if (tid < D) { g_s[tid] = g1[tid]; b_s[tid] = be1[tid]; }
    __syncthreads();

    const int gid = blockIdx.x * 256 + tid;
    const int eh  = gid & 1;            // e-half: 0 -> e 0..4, 1 -> e 5..9
    const int h   = (gid >> 1) & 3;
    const int row = gid >> 3;

    float xr[D];
    const float4* xp = reinterpret_cast<const float4*>(x + (size_t)row * D);
    #pragma unroll
    for (int i = 0; i < D/4; ++i) {
        float4 t4 = xp[i];
        xr[4*i+0]=t4.x; xr[4*i+1]=t4.y; xr[4*i+2]=t4.z; xr[4*i+3]=t4.w;
    }
    float mu = 0.f;
    #pragma unroll
    for (int d = 0; d < D; ++d) mu += xr[d];
    mu *= (1.f/D);
    float var = 0.f;
    #pragma unroll
    for (int d = 0; d < D; ++d) { float dd = xr[d]-mu; var += dd*dd; }
    var *= (1.f/D);
    const float rs = rsqrtf(var + 1e-5f);
    #pragma unroll
    for (int d = 0; d < D; ++d) xr[d] = (xr[d]-mu)*rs*g_s[d] + b_s[d];

    if ((gid & 7) == 0) {
        float4* xo = reinterpret_cast<float4*>(xn + (size_t)row * D);
        #pragma unroll
        for (int i = 0; i < D/4; ++i) {
            float4 t4; t4.x=xr[4*i+0]; t4.y=xr[4*i+1]; t4.z=xr[4*i+2]; t4.w=xr[4*i+3];
            xo[i] = t4;
        }
    }

    const int b = row >> 11;
    const int t = row & (TT-1);
    const int bh = b*NH + h;
    const int e0 = eh * 5;

    float aq[5], ak[5], av[5];
    #pragma unroll
    for (int e = 0; e < 5; ++e) {
        aq[e] = dot40(xr, &wt_s[(h*HS + e0 + e)*D]);
        ak[e] = dot40(xr, &wt_s[NH*HS*D + (h*HS + e0 + e)*D]);
        av[e] = dot40(xr, &wt_s[2*NH*HS*D + (h*HS + e0 + e)*D]);
    }

    // exchange: eh0 sends its k-lows (partner needs them), eh1 sends q-highs.
    float send[5], recv[5];
    #pragma unroll
    for (int j = 0; j < 5; ++j) send[j] = eh ? aq[j] : ak[j];
    #pragma unroll
    for (int j = 0; j < 5; ++j) recv[j] = __shfl_xor(send[j], 1);

    // eh0 owns the full q row (scaled by log2 e); eh1 owns the full k row
    const float scale = eh ? 1.f : LOG2E;
    float lo[5], hi[5];
    #pragma unroll
    for (int j = 0; j < 5; ++j) {
        lo[j] = eh ? recv[j] : aq[j];
        hi[j] = eh ? ak[j]   : recv[j];
    }
    union { unsigned short u[PE]; uint4 v4[2]; } U;
    #pragma unroll
    for (int e = 0; e < PE; ++e)
        U.u[e] = (e < 5) ? f2b(lo[e]*scale)
               : (e < 10) ? f2b(hi[e-5]*scale) : (unsigned short)0;
    unsigned short* dst = (eh ? kb : qb) + ((size_t)bh*TT + t)*PE;
    uint4* d4 = reinterpret_cast<uint4*>(dst);
    d4[0] = U.v4[0]; d4[1] = U.v4[1];

    #pragma unroll
    for (int e = 0; e < 5; ++e)
        vT[((size_t)bh*VR + e0 + e)*TT + t] = f2b(av[e]);
    if (eh) vT[((size_t)bh*VR + HS)*TT + t] = 0x3F80;   // ones row -> l via MFMA
}

// ------- Kernel 2: MFMA flash attention ----------
// R6-proven structure with predicated loads (exec-masked-off loads are free).
// Scores bounded: p = 2^(s') with q pre-scaled by log2(e); l free via the
// ones-row of V^T (output row 10).
__global__ __launch_bounds__(256, 4) void k_attn(
    const unsigned short* __restrict__ qb, const unsigned short* __restrict__ kb,
    const unsigned short* __restrict__ vT, float* __restrict__ ao)
{
    __shared__ __align__(16) unsigned short PT[4][16][40];  // 80B row: 16B-aligned, ~2-way banks
    const int w    = threadIdx.x >> 6;
    const int lane = threadIdx.x & 63;
    const int g    = lane >> 4;
    const int li   = lane & 15;
    const int bh   = blockIdx.y;
    const int i0   = blockIdx.x * 64 + w * 16;
    const size_t bT = (size_t)bh * TT;

    const bf16x8 zero8 = {0,0,0,0,0,0,0,0};
    const f32x4  zacc  = {0.f,0.f,0.f,0.f};

    bf16x8 kf = zero8;                       // B-frag: k[i0+li][8g..8g+7]
    if (g < 2) kf = *reinterpret_cast<const bf16x8*>(kb + (bT + i0 + li)*PE + 8*g);

    f32x4 acc = zacc;
    const unsigned short* vrow = vT + ((size_t)bh*VR + (li <= HS ? li : 0))*TT;

    #pragma unroll 4
    for (int jt = 0; jt < TT; jt += 32) {
        bf16x8 a0 = zero8, a1 = zero8;       // A-frags: q[jt+li], q[jt+16+li]
        if (g < 2) {
            a0 = *reinterpret_cast<const bf16x8*>(qb + (bT + jt      + li)*PE + 8*g);
            a1 = *reinterpret_cast<const bf16x8*>(qb + (bT + jt + 16 + li)*PE + 8*g);
        }
        __builtin_amdgcn_s_setprio(1);
        f32x4 s0 = __builtin_amdgcn_mfma_f32_16x16x32_bf16(a0, kf, zacc, 0, 0, 0);
        f32x4 s1 = __builtin_amdgcn_mfma_f32_16x16x32_bf16(a1, kf, zacc, 0, 0, 0);
        __builtin_amdgcn_s_setprio(0);

        const float p0 = __builtin_amdgcn_exp2f(s0[0]), p1 = __builtin_amdgcn_exp2f(s0[1]);
        const float p2 = __builtin_amdgcn_exp2f(s0[2]), p3 = __builtin_amdgcn_exp2f(s0[3]);
        const float p4 = __builtin_amdgcn_exp2f(s1[0]), p5 = __builtin_amdgcn_exp2f(s1[1]);
        const float p6 = __builtin_amdgcn_exp2f(s1[2]), p7 = __builtin_amdgcn_exp2f(s1[3]);

        unsigned int w0, w1, w2, w3;
        asm("v_cvt_pk_bf16_f32 %0, %1, %2" : "=v"(w0) : "v"(p0), "v"(p1));
        asm("v_cvt_pk_bf16_f32 %0, %1, %2" : "=v"(w1) : "v"(p2), "v"(p3));
        asm("v_cvt_pk_bf16_f32 %0, %1, %2" : "=v"(w2) : "v"(p4), "v"(p5));
        asm("v_cvt_pk_bf16_f32 %0, %1, %2" : "=v"(w3) : "v"(p6), "v"(p7));
        *reinterpret_cast<uint2*>(&PT[w][li][4*g])      = make_uint2(w0, w1);
        *reinterpret_cast<uint2*>(&PT[w][li][16 + 4*g]) = make_uint2(w2, w3);

        bf16x8 pf = *reinterpret_cast<const bf16x8*>(&PT[w][li][8*g]);
        bf16x8 vf = zero8;
        if (li <= HS) vf = *reinterpret_cast<const bf16x8*>(vrow + jt + 8*g);
        __builtin_amdgcn_s_setprio(1);
        acc = __builtin_amdgcn_mfma_f32_16x16x32_bf16(vf, pf, acc, 0, 0, 0);
        __builtin_amdgcn_s_setprio(0);
    }

    // l for column li lives in acc[2] of lane (g=2, li)  [row 10 = ones row]
    const float l = __shfl(acc[2], 32 + li);
    const float linv = 1.f / l;
    float* orow = ao + (bT + i0 + li) * HS;
    #pragma unroll
    for (int r = 0; r < 4; ++r) {
        const int e = 4*g + r;               // O^T row = e, col = i (lane-local)
        if (e < HS) orow[e] = acc[r] * linv;
    }
}

// ------- Kernel 3: epilogue, 4 threads per row ------------------------------
__global__ __launch_bounds__(256) void k_epilogue(
    const float* __restrict__ attn, const float* __restrict__ xn,
    const float* __restrict__ Wp, const float* __restrict__ bp,
    const float* __restrict__ W1, const float* __restrict__ b1,
    const float* __restrict__ W2, const float* __restrict__ b2,
    const float* __restrict__ g2, const float* __restrict__ be2,
    float* __restrict__ out)
{
    __shared__ float wp_s[D*D], w1_s[D*D], w2_s[D*D];
    __shared__ float bp_s[D], b1_s[D], b2_s[D], g_s[D], be_s[D];
    const int tid = threadIdx.x;
    {
        float4* wp4 = reinterpret_cast<float4*>(wp_s);
        float4* w14 = reinterpret_cast<float4*>(w1_s);
        float4* w24 = reinterpret_cast<float4*>(w2_s);
        const float4* Wp4 = reinterpret_cast<const float4*>(Wp);
        const float4* W14 = reinterpret_cast<const float4*>(W1);
        const float4* W24 = reinterpret_cast<const float4*>(W2);
        for (int i = tid; i < D*D/4; i += 256) {
            wp4[i] = Wp4[i]; w14[i] = W14[i]; w24[i] = W24[i];
        }
    }
    if (tid < D) {
        bp_s[tid]=bp[tid]; b1_s[tid]=b1[tid]; b2_s[tid]=b2[tid];
        g_s[tid]=g2[tid]; be_s[tid]=be2[tid];
    }
    __syncthreads();

    const int gid  = blockIdx.x * 256 + tid;
    const int row  = gid >> 2;
    const int q4   = gid & 3;
    const int b0   = q4 * 10;
    const int lane = tid & 63;
    const int base = lane & 60;          // first lane of this row's 4-lane group
    const int b    = row >> 11;
    const int t    = row & (TT-1);

    float cat[D];
    #pragma unroll
    for (int h = 0; h < NH; ++h) {
        const float2* ap = reinterpret_cast<const float2*>(
            attn + ((((size_t)b*NH + h)*TT) + t)*HS);
        #pragma unroll
        for (int e = 0; e < HS/2; ++e) {
            float2 t2 = ap[e];
            cat[h*HS + 2*e] = t2.x; cat[h*HS + 2*e + 1] = t2.y;
        }
    }

    float y[10];
    {
        const float2* xp = reinterpret_cast<const float2*>(xn + (size_t)row*D + b0);
        #pragma unroll
        for (int i = 0; i < 5; ++i) {
            float2 t2 = xp[i];
            y[2*i+0] = t2.x; y[2*i+1] = t2.y;
        }
    }
    #pragma unroll
    for (int d = 0; d < 10; ++d) y[d] += bp_s[b0+d];
    for (int c = 0; c < D; ++c) {
        const float cc = cat[c];
        const float* wr = &wp_s[c*D + b0];
        #pragma unroll
        for (int d = 0; d < 10; ++d) y[d] = fmaf(cc, wr[d], y[d]);
    }

    // LN2 via 4-lane reduce
    float sp = 0.f;
    #pragma unroll
    for (int d = 0; d < 10; ++d) sp += y[d];
    sp += __shfl_xor(sp, 1); sp += __shfl_xor(sp, 2);
    const float mu = sp * (1.f/D);
    float vp = 0.f;
    #pragma unroll
    for (int d = 0; d < 10; ++d) { float dd = y[d]-mu; vp += dd*dd; }
    vp += __shfl_xor(vp, 1); vp += __shfl_xor(vp, 2);
    const float rs = rsqrtf(vp * (1.f/D) + 1e-5f);

    float y2[10];
    #pragma unroll
    for (int d = 0; d < 10; ++d) y2[d] = (y[d]-mu)*rs*g_s[b0+d] + be_s[b0+d];

    float z[D];
    #pragma unroll
    for (int seg = 0; seg < 4; ++seg)
        #pragma unroll
        for (int j = 0; j < 10; ++j)
            z[seg*10 + j] = __shfl(y2[j], base + seg);

    float hd[10];
    #pragma unroll
    for (int d = 0; d < 10; ++d) hd[d] = b1_s[b0+d];
    for (int c = 0; c < D; ++c) {
        const float cc = z[c];
        const float* wr = &w1_s[c*D + b0];
        #pragma unroll
        for (int d = 0; d < 10; ++d) hd[d] = fmaf(cc, wr[d], hd[d]);
    }
    #pragma unroll
    for (int d = 0; d < 10; ++d) hd[d] = fmaxf(hd[d], 0.f);

    float hf[D];
    #pragma unroll
    for (int seg = 0; seg < 4; ++seg)
        #pragma unroll
        for (int j = 0; j < 10; ++j)
            hf[seg*10 + j] = __shfl(hd[j], base + seg);

    float ov[10];
    #pragma unroll
    for (int d = 0; d < 10; ++d) ov[d] = y2[d] + b2_s[b0+d];
    for (int c = 0; c < D; ++c) {
        const float cc = hf[c];
        const float* wr = &w2_s[c*D + b0];
        #pragma unroll
        for (int d = 0; d < 10; ++d) ov[d] = fmaf(cc, wr[d], ov[d]);
    }

    float2* op = reinterpret_cast<float2*>(out + (size_t)row*D + b0);
    #pragma unroll
    for (int i = 0; i < 5; ++i) {
        float2 t2; t2.x = ov[2*i]; t2.y = ov[2*i+1];
        op[i] = t2;
    }
}

} // namespace

extern "C" void kernel_launch(void* const* d_in, const int* in_sizes, int n_in,
                              void* d_out, int out_size, void* d_ws, size_t ws_size,
                              hipStream_t stream) {
    const float* x   = (const float*)d_in[0];
    const float* Wq  = (const float*)d_in[1];
    const float* Wk  = (const float*)d_in[2];
    const float* Wv  = (const float*)d_in[3];
    const float* Wp  = (const float*)d_in[4];
    const float* bp  = (const float*)d_in[5];
    const float* W1  = (const float*)d_in[6];
    const float* b1  = (const float*)d_in[7];
    const float* W2  = (const float*)d_in[8];
    const float* b2  = (const float*)d_in[9];
    const float* g1  = (const float*)d_in[10];
    const float* be1 = (const float*)d_in[11];
    const float* g2  = (const float*)d_in[12];
    const float* be2 = (const float*)d_in[13];

    const size_t N = (size_t)ROWS * D;           // 1,310,720
    float* xn = (float*)d_ws;                    // [ROWS][40] f32
    float* ao = xn + N;                          // [64][2048][10] f32
    unsigned short* qb = (unsigned short*)(ao + N);        // [64][2048][16] bf16
    unsigned short* kb = qb + (size_t)BB*NH*TT*PE;
    unsigned short* vT = kb + (size_t)BB*NH*TT*PE;         // [64][11][2048] bf16

    k_ln_qkv<<<ROWS*8/256, 256, 0, stream>>>(x, Wq, Wk, Wv, g1, be1, xn, qb, kb, vT);
    k_attn<<<dim3(TT/64, BB*NH), 256, 0, stream>>>(qb, kb, vT, ao);
    k_epilogue<<<ROWS*4/256, 256, 0, stream>>>(ao, xn, Wp, bp, W1, b1, W2, b2, g2, be2,
                                               (float*)d_out);
}